// Round 4
// baseline (165.705 us; speedup 1.0000x reference)
//
#include <hip/hip_runtime.h>

typedef unsigned short u16;
typedef unsigned int u32;

typedef __attribute__((ext_vector_type(8))) short bf16x8;
typedef __attribute__((ext_vector_type(4))) float f32x4;

#define BSH 8          // bucket shift: 256 nodes per bucket
#define CAP 5120       // staging capacity per bucket (mean 4081 at E=800k, +16 sigma)
#define OVFCAP 8192
#define CHUNK 2048     // edges per binA2 block (2 per thread at 1024 threads)
#define SEGCAP 6144    // LDS csr segment buffer (mean 4096, +32 sigma); tail -> direct

__device__ __forceinline__ float bf2f(u16 u) {
    return __uint_as_float(((u32)u) << 16);
}
__device__ __forceinline__ u16 f2bf(float f) {
    u32 x = __float_as_uint(f);
    return (u16)((x + 0x7fffu + ((x >> 16) & 1u)) >> 16);
}

// block-uniform dtype flag: true if x is bf16, false if fp32.
__device__ __forceinline__ bool block_isbf(const u16* __restrict__ x, float* sflag) {
    int tid = threadIdx.x;
    if (tid < 64) {
        u16 v = x[tid * 2];
        u32 ex = (v >> 7) & 0xFFu;
        unsigned long long m = __ballot(ex >= 90u && ex <= 140u);
        if (tid == 0) *sflag = (m == ~0ull) ? 1.0f : 0.0f;
    }
    __syncthreads();
    return *sflag != 0.0f;
}

__device__ __forceinline__ void acc8(uint4 w, float* a) {
    a[0] += bf2f((u16)(w.x & 0xFFFFu)); a[1] += bf2f((u16)(w.x >> 16));
    a[2] += bf2f((u16)(w.y & 0xFFFFu)); a[3] += bf2f((u16)(w.y >> 16));
    a[4] += bf2f((u16)(w.z & 0xFFFFu)); a[5] += bf2f((u16)(w.z >> 16));
    a[6] += bf2f((u16)(w.w & 0xFFFFu)); a[7] += bf2f((u16)(w.w >> 16));
}

// Bin edges into per-bucket staging. NO per-node atomics; single pass.
// 1024 threads/block (2 edges/thread): ~24 waves/CU avg for latency hiding.
// bucket(d) = d >> BSH. Entry: src | (d&255)<<16.
__global__ __launch_bounds__(1024) void k_binA2(
    const int* __restrict__ src, const int* __restrict__ dst,
    int* __restrict__ gcur, u32* __restrict__ staging,
    u32* __restrict__ ovf, int* __restrict__ ovfcur, int E) {
    __shared__ int hcnt[256];
    __shared__ int hbase[256];
    const int tid = threadIdx.x;
    const int e0 = blockIdx.x * CHUNK;
    const int e1 = min(e0 + CHUNK, E);
    if (tid < 256) hcnt[tid] = 0;
    __syncthreads();
    int dl[2], sl[2];
    const int eb = e0 + tid * 2;
    const bool vec = (eb + 1 < e1) &&
                     ((((size_t)(dst + eb)) | ((size_t)(src + eb))) & 7) == 0;
    if (vec) {
        int2 d2 = *(const int2*)(dst + eb);
        int2 s2 = *(const int2*)(src + eb);
        dl[0] = d2.x; dl[1] = d2.y;
        sl[0] = s2.x; sl[1] = s2.y;
    } else {
#pragma unroll
        for (int k = 0; k < 2; k++) {
            int e = eb + k;
            bool ok = e < e1;
            dl[k] = ok ? dst[e] : -1;
            sl[k] = ok ? src[e] : 0;
        }
    }
#pragma unroll
    for (int k = 0; k < 2; k++)
        if (dl[k] >= 0) atomicAdd(&hcnt[dl[k] >> BSH], 1);
    __syncthreads();
    if (tid < 256) {
        int c = hcnt[tid];
        hbase[tid] = (c > 0) ? atomicAdd(&gcur[tid], c) : 0;
        hcnt[tid] = 0;                   // reuse as local cursor
    }
    __syncthreads();
#pragma unroll
    for (int k = 0; k < 2; k++) {
        int d = dl[k];
        if (d < 0) continue;
        int b = d >> BSH;
        int r = atomicAdd(&hcnt[b], 1);
        int p = hbase[b] + r;
        if (p < CAP) {
            staging[(size_t)b * CAP + p] = (u32)sl[k] | ((u32)(d & 255) << 16);
        } else {
            int q = atomicAdd(ovfcur, 1);
            if (q < OVFCAP) ovf[q] = (u32)sl[k] | ((u32)d << 16);
        }
    }
}

// Per-bucket counting sort. One 1024-thread block per bucket.
// Staging is read ONCE into registers (<=2 uint4/thread + scalar tail), feeding
// both the hist and the fill. csr goes through an LDS segment buffer for
// coalesced global writes. Blocks [nbuck, nbuck+17): weight canonicalization.
// wc layout (u16): [0,8192) W1t[n*64+k] | [8192,16384) W2t[n*128+k]
//                  [16384,16512) b1 | [16512,16576) b2
__global__ __launch_bounds__(1024) void k_bucket(
    const u32* __restrict__ staging, const int* __restrict__ gcur,
    const u32* __restrict__ ovf, const int* __restrict__ ovfcur,
    int* __restrict__ row_start, float* __restrict__ dinv,
    u16* __restrict__ csr, int nbuck,
    const void* __restrict__ W1, const void* __restrict__ b1,
    const void* __restrict__ W2, const void* __restrict__ b2,
    u16* __restrict__ wc,
    const void* __restrict__ x, u16* __restrict__ gxt, int N, int E) {
    __shared__ float sflag;
    __shared__ int hcnt[256];
    __shared__ int hscan[256];
    __shared__ int hcur[256];
    __shared__ int sred[256];
    __shared__ int sbase;
    __shared__ float sdinv[256];
    __shared__ u16 seg_lds[SEGCAP];   // 12 KB: cursor-ordered csr segment
    const int bid = blockIdx.x;
    const int tid = threadIdx.x;
    bool isbf = block_isbf((const u16*)x, &sflag);

    if (bid < nbuck) {
        const int b = bid;
        const int used = min(gcur[b], CAP);
        const u32* st = staging + (size_t)b * CAP;
        const int no = min(ovfcur[0], OVFCAP);
        const int used4 = used >> 2;
        // bucket base = sum gcur[0..b)
        if (tid < 256) {
            sred[tid] = (tid < b) ? gcur[tid] : 0;
            hcnt[tid] = 0;
        }
        __syncthreads();
        for (int s = 128; s > 0; s >>= 1) {
            if (tid < s) sred[tid] += sred[tid + s];
            __syncthreads();
        }
        if (tid == 0) sbase = sred[0];
        // register-cache staging (single global read feeds hist AND fill)
        const int i0 = tid, i1 = 1024 + tid;
        const bool h0 = i0 < used4, h1 = i1 < used4;
        uint4 r0v = h0 ? ((const uint4*)st)[i0] : make_uint4(0, 0, 0, 0);
        uint4 r1v = h1 ? ((const uint4*)st)[i1] : make_uint4(0, 0, 0, 0);
        const int ti = (used4 << 2) + tid;
        const bool ht = ti < used;
        u32 tv = ht ? st[ti] : 0u;
        // pass1: per-node hist
        if (h0) {
            atomicAdd(&hcnt[r0v.x >> 16], 1);
            atomicAdd(&hcnt[r0v.y >> 16], 1);
            atomicAdd(&hcnt[r0v.z >> 16], 1);
            atomicAdd(&hcnt[r0v.w >> 16], 1);
        }
        if (h1) {
            atomicAdd(&hcnt[r1v.x >> 16], 1);
            atomicAdd(&hcnt[r1v.y >> 16], 1);
            atomicAdd(&hcnt[r1v.z >> 16], 1);
            atomicAdd(&hcnt[r1v.w >> 16], 1);
        }
        if (ht) atomicAdd(&hcnt[tv >> 16], 1);
        for (int i = tid; i < no; i += 1024) {
            u32 pk = ovf[i];
            int d = (int)(pk >> 16);
            if ((d >> BSH) == b) atomicAdd(&hcnt[d & 255], 1);
        }
        __syncthreads();
        // exclusive scan over 256 counts (guarded; barriers uniform)
        int v = 0;
        if (tid < 256) {
            v = hcnt[tid];
            hscan[tid] = v;
        }
        __syncthreads();
        for (int s = 1; s < 256; s <<= 1) {
            int t = (tid < 256 && tid >= s) ? hscan[tid - s] : 0;
            __syncthreads();
            if (tid < 256) hscan[tid] += t;
            __syncthreads();
        }
        if (tid < 256) {
            int excl = hscan[tid] - v;
            hcur[tid] = excl;
            float dv = rsqrtf((float)(v + 1));
            sdinv[tid] = dv;
            int node = (b << BSH) + tid;
            if (node < N) {
                row_start[node] = sbase + excl;
                dinv[node] = dv;
            }
        }
        if (b == 0 && tid == 0) row_start[N] = E;
        __syncthreads();
        const int base = sbase;
        // pass2: csr fill from registers via LDS cursors into LDS segment
        if (h0) {
            int r0 = atomicAdd(&hcur[r0v.x >> 16], 1);
            u16 w0 = (u16)(r0v.x & 0xFFFFu);
            if (r0 < SEGCAP) seg_lds[r0] = w0; else csr[base + r0] = w0;
            int r1 = atomicAdd(&hcur[r0v.y >> 16], 1);
            u16 w1 = (u16)(r0v.y & 0xFFFFu);
            if (r1 < SEGCAP) seg_lds[r1] = w1; else csr[base + r1] = w1;
            int r2 = atomicAdd(&hcur[r0v.z >> 16], 1);
            u16 w2 = (u16)(r0v.z & 0xFFFFu);
            if (r2 < SEGCAP) seg_lds[r2] = w2; else csr[base + r2] = w2;
            int r3 = atomicAdd(&hcur[r0v.w >> 16], 1);
            u16 w3 = (u16)(r0v.w & 0xFFFFu);
            if (r3 < SEGCAP) seg_lds[r3] = w3; else csr[base + r3] = w3;
        }
        if (h1) {
            int r0 = atomicAdd(&hcur[r1v.x >> 16], 1);
            u16 w0 = (u16)(r1v.x & 0xFFFFu);
            if (r0 < SEGCAP) seg_lds[r0] = w0; else csr[base + r0] = w0;
            int r1 = atomicAdd(&hcur[r1v.y >> 16], 1);
            u16 w1 = (u16)(r1v.y & 0xFFFFu);
            if (r1 < SEGCAP) seg_lds[r1] = w1; else csr[base + r1] = w1;
            int r2 = atomicAdd(&hcur[r1v.z >> 16], 1);
            u16 w2 = (u16)(r1v.z & 0xFFFFu);
            if (r2 < SEGCAP) seg_lds[r2] = w2; else csr[base + r2] = w2;
            int r3 = atomicAdd(&hcur[r1v.w >> 16], 1);
            u16 w3 = (u16)(r1v.w & 0xFFFFu);
            if (r3 < SEGCAP) seg_lds[r3] = w3; else csr[base + r3] = w3;
        }
        if (ht) {
            int r = atomicAdd(&hcur[tv >> 16], 1);
            u16 w = (u16)(tv & 0xFFFFu);
            if (r < SEGCAP) seg_lds[r] = w; else csr[base + r] = w;
        }
        for (int i = tid; i < no; i += 1024) {
            u32 pk = ovf[i];
            int d = (int)(pk >> 16);
            if ((d >> BSH) == b) {
                int r = atomicAdd(&hcur[d & 255], 1);
                u16 w = (u16)(pk & 0xFFFFu);
                if (r < SEGCAP) seg_lds[r] = w; else csr[base + r] = w;
            }
        }
        __syncthreads();
        // coalesced dump of the segment
        {
            int seg = min(hscan[255], SEGCAP);
            for (int i = tid; i < seg; i += 1024) csr[base + i] = seg_lds[i];
        }
        // scale_x for our 256 rows: gxt[row] = bf16(x[row] * dinv[row])
        const int row0 = b << BSH;
        for (int i = tid; i < 256 * 16; i += 1024) {
            int rl = i >> 4;
            int node2 = row0 + rl;
            if (node2 >= N) continue;
            int q = i & 15;
            size_t idx = (size_t)node2 * 16 + q;
            float di = sdinv[rl];
            float4 vv;
            if (isbf) {
                ushort4 u = ((const ushort4*)x)[idx];
                vv.x = bf2f(u.x); vv.y = bf2f(u.y); vv.z = bf2f(u.z); vv.w = bf2f(u.w);
            } else {
                vv = ((const float4*)x)[idx];
            }
            ushort4 o;
            o.x = f2bf(vv.x * di); o.y = f2bf(vv.y * di);
            o.z = f2bf(vv.z * di); o.w = f2bf(vv.w * di);
            ((ushort4*)gxt)[idx] = o;
        }
    } else {
        // weight canonicalize (17 blocks, one stride covers 16576)
        int cb = bid - nbuck;
        for (int i = cb * 1024 + tid; i < 16576; i += 17 * 1024) {
            const void* s; int off;
            if (i < 8192)       { int nn = i >> 6, k = i & 63;  s = W1; off = k * 128 + nn; }
            else if (i < 16384) { int j = i - 8192; int nn = j >> 7, k = j & 127; s = W2; off = k * 64 + nn; }
            else if (i < 16512) { s = b1; off = i - 16384; }
            else                { s = b2; off = i - 16512; }
            wc[i] = isbf ? ((const u16*)s)[off] : f2bf(((const float*)s)[off]);
        }
    }
}

// gather: acc[d] = feat[d] + sum_{j in in(d)} feat[csr[j]], then *dinv[d]
// (+b2 and dtype-matched output when FINAL).
// 4 lanes/node x 2 sequential COLUMN-HALVES: each half-table is 3.2 MB and
// fits a per-XCD L2 (4 MB) -> random row reads become L2 hits. Blocks are
// ~all co-resident, so the device is phase-coherent on one half at a time.
// 8 row-loads per lane stay in flight (two csr pipeline regs) == same MLP as
// the previous 8-lane/node version. Per-element FP add order is unchanged.
template<bool FINAL>
__global__ __launch_bounds__(256) void k_gather(
    const uint4* __restrict__ feat, const int* __restrict__ row_start,
    const u16* __restrict__ csr, const float* __restrict__ dinv,
    const u16* __restrict__ b2c, const void* __restrict__ xdet,
    void* __restrict__ outp, int n) {
    __shared__ float sflag;
    bool isbf = true;
    if (FINAL) isbf = block_isbf((const u16*)xdet, &sflag);
    int t = blockIdx.x * 256 + threadIdx.x;
    int d = t >> 2;
    int lane = t & 3;            // 4 lanes/node, lane covers 8 feats of each half
    if (d >= n) return;
    const int s0 = row_start[d], s1 = row_start[d + 1];
    const float di = dinv[d];
#pragma unroll
    for (int h = 0; h < 2; h++) {
        const uint4* fl = feat + h * 4 + lane;   // row = 8 uint4; half h = 4 of them
        float a[8];
        {
            uint4 w = fl[(size_t)d * 8];         // self-loop
            a[0] = bf2f((u16)(w.x & 0xFFFFu)); a[1] = bf2f((u16)(w.x >> 16));
            a[2] = bf2f((u16)(w.y & 0xFFFFu)); a[3] = bf2f((u16)(w.y >> 16));
            a[4] = bf2f((u16)(w.z & 0xFFFFu)); a[5] = bf2f((u16)(w.z >> 16));
            a[6] = bf2f((u16)(w.w & 0xFFFFu)); a[7] = bf2f((u16)(w.w >> 16));
        }
        int j = s0;
        int c0 = (j + lane < s1) ? (int)csr[j + lane] : 0;
        int c1 = (j + 4 + lane < s1) ? (int)csr[j + 4 + lane] : 0;
        while (j + 8 <= s1) {
            int n0 = (j + 8 + lane < s1) ? (int)csr[j + 8 + lane] : 0;
            int n1 = (j + 12 + lane < s1) ? (int)csr[j + 12 + lane] : 0;
            uint4 wv[8];
#pragma unroll
            for (int u = 0; u < 4; u++) {
                int sv = __shfl(c0, u, 4);
                wv[u] = fl[(size_t)sv * 8];
            }
#pragma unroll
            for (int u = 0; u < 4; u++) {
                int sv = __shfl(c1, u, 4);
                wv[4 + u] = fl[(size_t)sv * 8];
            }
#pragma unroll
            for (int u = 0; u < 8; u++) acc8(wv[u], a);
            c0 = n0; c1 = n1;
            j += 8;
        }
        int rem = s1 - j;
        for (int u = 0; u < rem; u++) {
            int sv = (u < 4) ? __shfl(c0, u, 4) : __shfl(c1, u - 4, 4);
            uint4 wv = fl[(size_t)sv * 8];
            acc8(wv, a);
        }
        if (FINAL) {
#pragma unroll
            for (int u = 0; u < 8; u++)
                a[u] = a[u] * di + bf2f(b2c[h * 32 + lane * 8 + u]);
            if (isbf) {
                uint4 o;
                o.x = (u32)f2bf(a[0]) | ((u32)f2bf(a[1]) << 16);
                o.y = (u32)f2bf(a[2]) | ((u32)f2bf(a[3]) << 16);
                o.z = (u32)f2bf(a[4]) | ((u32)f2bf(a[5]) << 16);
                o.w = (u32)f2bf(a[6]) | ((u32)f2bf(a[7]) << 16);
                ((uint4*)outp)[(size_t)d * 8 + h * 4 + lane] = o;
            } else {
                float4* op = (float4*)outp;
                op[(size_t)d * 16 + h * 8 + 2 * lane]     = make_float4(a[0], a[1], a[2], a[3]);
                op[(size_t)d * 16 + h * 8 + 2 * lane + 1] = make_float4(a[4], a[5], a[6], a[7]);
            }
        } else {
            // single rounding: fp32 acc * dinv -> bf16 (k_mlp consumes directly)
            uint4 o;
            o.x = (u32)f2bf(a[0] * di) | ((u32)f2bf(a[1] * di) << 16);
            o.y = (u32)f2bf(a[2] * di) | ((u32)f2bf(a[3] * di) << 16);
            o.z = (u32)f2bf(a[4] * di) | ((u32)f2bf(a[5] * di) << 16);
            o.w = (u32)f2bf(a[6] * di) | ((u32)f2bf(a[7] * di) << 16);
            ((uint4*)outp)[(size_t)d * 8 + h * 4 + lane] = o;
        }
    }
}

// MFMA fused 2-layer MLP on a 64-row tile, in-place safe:
//   h   = relu( As @ W1 + b1 )   As = bf16-prescaled acc1   [64 x 128]
//   ht2 = ( h @ W2 ) * dinv[r]                              [64 x 64] -> bf16 outb
// LDS: W2t overlaps the As+W1t region (dead after GEMM1); W2 parked in 16 VGPRs
// during GEMM1. 44.8 KB LDS -> 3 blocks/CU.
__global__ __launch_bounds__(256, 3) void k_mlp(
    const u16* __restrict__ accin, const u16* __restrict__ wc,
    const float* __restrict__ dinv, u16* outb, int n) {
    __shared__ __align__(16) u16 U[64 * 72 + 128 * 72];   // 27.0 KB: As | W1t ; W2t aliases
    __shared__ __align__(16) u16 Hs[64 * 136];            // 17.0 KB
    __shared__ float b1s[128];
    __shared__ float dvs[64];
    u16* As  = U;                  // 64 x 72
    u16* W1t = U + 64 * 72;        // 128 x 72
    u16* W2t = U;                  // 64 x 136 (17408 B <= 27648 B), live after GEMM1

    const int tid = threadIdx.x;
    const int row0 = blockIdx.x * 64;

    // stage W1t, b1s, dvs
    for (int i = tid; i < 1024; i += 256) {
        int nn = i >> 3, kk = i & 7;
        *(uint4*)&W1t[nn * 72 + kk * 8] = ((const uint4*)wc)[i];
    }
    if (tid < 128) b1s[tid] = bf2f(wc[16384 + tid]);
    if (tid < 64) {
        int r = row0 + tid;
        dvs[tid] = (r < n) ? dinv[r] : 0.f;
    }
    // As: 64 rows x 8 uint4 (acc1 already dinv-prescaled by k_gather<false>)
    for (int i = tid; i < 512; i += 256) {
        int r = i >> 3, kk = i & 7;
        int row = row0 + r;
        uint4 v = make_uint4(0, 0, 0, 0);
        if (row < n) v = ((const uint4*)accin)[(size_t)row * 8 + kk];
        *(uint4*)&As[r * 72 + kk * 8] = v;
    }
    // park W2 in registers (L2-hot; written to LDS after GEMM1 frees the region)
    uint4 wreg[4];
#pragma unroll
    for (int u = 0; u < 4; u++) wreg[u] = ((const uint4*)(wc + 8192))[tid + 256 * u];

    __syncthreads();

    const int wave = tid >> 6;     // 0..3
    const int lane = tid & 63;
    const int q = lane >> 4;       // quad
    const int ln = lane & 15;

    // ---- GEMM1: [64x64] @ [64x128] ----
    bf16x8 a[4][2];
#pragma unroll
    for (int mt = 0; mt < 4; mt++)
#pragma unroll
        for (int ks = 0; ks < 2; ks++)
            a[mt][ks] = *(const bf16x8*)&As[(mt * 16 + ln) * 72 + ks * 32 + q * 8];

    f32x4 c1[2][4];   // [ntl][mt]
#pragma unroll
    for (int ntl = 0; ntl < 2; ntl++)
#pragma unroll
        for (int mt = 0; mt < 4; mt++) c1[ntl][mt] = (f32x4){0.f, 0.f, 0.f, 0.f};

    __builtin_amdgcn_s_setprio(1);
#pragma unroll
    for (int ntl = 0; ntl < 2; ntl++) {
        int nt = wave * 2 + ntl;
        bf16x8 b0 = *(const bf16x8*)&W1t[(nt * 16 + ln) * 72 + 0 + q * 8];
        bf16x8 b1f = *(const bf16x8*)&W1t[(nt * 16 + ln) * 72 + 32 + q * 8];
#pragma unroll
        for (int mt = 0; mt < 4; mt++) {
            c1[ntl][mt] = __builtin_amdgcn_mfma_f32_16x16x32_bf16(a[mt][0], b0, c1[ntl][mt], 0, 0, 0);
            c1[ntl][mt] = __builtin_amdgcn_mfma_f32_16x16x32_bf16(a[mt][1], b1f, c1[ntl][mt], 0, 0, 0);
        }
    }
    __builtin_amdgcn_s_setprio(0);
#pragma unroll
    for (int ntl = 0; ntl < 2; ntl++) {
        int col = (wave * 2 + ntl) * 16 + ln;
        float bb = b1s[col];
#pragma unroll
        for (int mt = 0; mt < 4; mt++)
#pragma unroll
            for (int r = 0; r < 4; r++) {
                int hrow = mt * 16 + q * 4 + r;
                Hs[hrow * 136 + col] = f2bf(fmaxf(c1[ntl][mt][r] + bb, 0.f));
            }
    }
    __syncthreads();               // all GEMM1 reads of As/W1t complete

    // write W2t into the freed As/W1t region
#pragma unroll
    for (int u = 0; u < 4; u++) {
        int i = tid + 256 * u;
        int nn = i >> 4, kk = i & 15;
        *(uint4*)&W2t[nn * 136 + kk * 8] = wreg[u];
    }
    __syncthreads();

    // ---- GEMM2: [64x128] @ [128x64] ----
    f32x4 c2[4];
#pragma unroll
    for (int mt = 0; mt < 4; mt++) c2[mt] = (f32x4){0.f, 0.f, 0.f, 0.f};
    __builtin_amdgcn_s_setprio(1);
#pragma unroll
    for (int ks = 0; ks < 4; ks++) {
        bf16x8 bb = *(const bf16x8*)&W2t[(wave * 16 + ln) * 136 + ks * 32 + q * 8];
#pragma unroll
        for (int mt = 0; mt < 4; mt++) {
            bf16x8 aa = *(const bf16x8*)&Hs[(mt * 16 + ln) * 136 + ks * 32 + q * 8];
            c2[mt] = __builtin_amdgcn_mfma_f32_16x16x32_bf16(aa, bb, c2[mt], 0, 0, 0);
        }
    }
    __builtin_amdgcn_s_setprio(0);
#pragma unroll
    for (int mt = 0; mt < 4; mt++)
#pragma unroll
        for (int r = 0; r < 4; r++) {
            int rloc = mt * 16 + q * 4 + r;
            int row = row0 + rloc;
            if (row < n) {
                int col = wave * 16 + ln;
                outb[(size_t)row * 64 + col] = f2bf(c2[mt][r] * dvs[rloc]);
            }
        }
}

extern "C" void kernel_launch(void* const* d_in, const int* in_sizes, int n_in,
                              void* d_out, int out_size, void* d_ws, size_t ws_size,
                              hipStream_t stream) {
    const void* x  = d_in[0];
    const int* ei  = (const int*)d_in[1];
    const void* W1 = d_in[2];
    const void* b1 = d_in[3];
    const void* W2 = d_in[4];
    const void* b2 = d_in[5];

    const int N = in_sizes[0] / 64;   // 50000 (< 65536 required: u16 csr + packing)
    const int E = in_sizes[1] / 2;    // 800000
    const int* src = ei;
    const int* dst = ei + E;

    // workspace (~8.5 MB of d_ws):
    //   dinv[NP] | gcur[256] | ovfcur[+pad 64] | row_start[N+64] | ovf[8192] u32
    //   | csr[E] u16 | wc[16576] u16 | bufB (N*64 u16)
    // staging (nbuck*CAP u32 ~4 MB) aliases bufB (dead until k_mlp writes it).
    // xt lives in d_out (scratch until k_gather<true> rewrites it).
    float* ws = (float*)d_ws;
    const int NP = ((N + 64) + 63) & ~63;
    float* dinv    = ws;
    int* gcur      = (int*)(ws + NP);
    int* ovfcur    = gcur + 256;
    int* row_start = gcur + 320;
    u32* ovf       = (u32*)(row_start + ((N + 64) & ~63));
    u16* csr       = (u16*)(ovf + OVFCAP);
    u16* wc        = (u16*)(((size_t)(csr + E) + 255) & ~(size_t)255);
    u16* bufB      = (u16*)(((size_t)(wc + 16576) + 255) & ~(size_t)255);
    u32* staging   = (u32*)bufB;
    u16* gxt       = (u16*)d_out;

    const int gth = (N * 4 + 255) / 256;       // gather grid (4 lanes/node, 2 halves)
    const int nbuck = (N + 255) >> BSH;        // 196 (<=256 required)
    const int binB = (E + CHUNK - 1) / CHUNK;  // 391
    dim3 blk(256);
    dim3 blk1k(1024);

    // zero gcur + ovfcur (graph-capture legal)
    hipMemsetAsync(gcur, 0, 320 * sizeof(int), stream);
    // bin edges into per-bucket staging (no per-node atomics, single-pass)
    k_binA2<<<dim3(binB), blk1k, 0, stream>>>(src, dst, gcur, staging, ovf, ovfcur, E);
    // per-bucket counting sort (row_start/dinv/csr) + scale_x + weight canon
    k_bucket<<<dim3(nbuck + 17), blk1k, 0, stream>>>(staging, gcur, ovf, ovfcur,
                                                     row_start, dinv, csr, nbuck,
                                                     W1, b1, W2, b2, wc, x, gxt, N, E);
    // acc1 = gather(xt)*dinv -> bufB (staging now dead)
    k_gather<false><<<dim3(gth), blk, 0, stream>>>((const uint4*)gxt, row_start, csr,
                                                   dinv, wc + 16512, x, bufB, N);
    // ht2 = (relu(acc1 @ W1 + b1) @ W2)*dinv -> bufB (in-place, row-local)
    k_mlp<<<dim3((N + 63) / 64), blk, 0, stream>>>((const u16*)bufB, wc, dinv, bufB, N);
    // out = bf16/f32( (ht2[d]+gather(ht2))*dinv + b2 ) -> d_out
    k_gather<true><<<dim3(gth), blk, 0, stream>>>((const uint4*)bufB, row_start, csr,
                                                  dinv, wc + 16512, x, d_out, N);
}

// Round 5
// 144.548 us; speedup vs baseline: 1.1464x; 1.1464x over previous
//
#include <hip/hip_runtime.h>

typedef unsigned short u16;
typedef unsigned int u32;

typedef __attribute__((ext_vector_type(8))) short bf16x8;
typedef __attribute__((ext_vector_type(4))) float f32x4;

#define BSH 8          // bucket shift: 256 nodes per bucket
#define CAP 5120       // staging capacity per bucket (mean 4081 at E=800k, +16 sigma)
#define OVFCAP 8192
#define CHUNK 2048     // edges per binA2 block (2 per thread at 1024 threads)
#define SEGCAP 6144    // LDS csr segment buffer (mean 4096, +32 sigma); tail -> direct

__device__ __forceinline__ float bf2f(u16 u) {
    return __uint_as_float(((u32)u) << 16);
}
__device__ __forceinline__ u16 f2bf(float f) {
    u32 x = __float_as_uint(f);
    return (u16)((x + 0x7fffu + ((x >> 16) & 1u)) >> 16);
}

// block-uniform dtype flag: true if x is bf16, false if fp32.
__device__ __forceinline__ bool block_isbf(const u16* __restrict__ x, float* sflag) {
    int tid = threadIdx.x;
    if (tid < 64) {
        u16 v = x[tid * 2];
        u32 ex = (v >> 7) & 0xFFu;
        unsigned long long m = __ballot(ex >= 90u && ex <= 140u);
        if (tid == 0) *sflag = (m == ~0ull) ? 1.0f : 0.0f;
    }
    __syncthreads();
    return *sflag != 0.0f;
}

__device__ __forceinline__ void acc8(uint4 w, float* a) {
    a[0] += bf2f((u16)(w.x & 0xFFFFu)); a[1] += bf2f((u16)(w.x >> 16));
    a[2] += bf2f((u16)(w.y & 0xFFFFu)); a[3] += bf2f((u16)(w.y >> 16));
    a[4] += bf2f((u16)(w.z & 0xFFFFu)); a[5] += bf2f((u16)(w.z >> 16));
    a[6] += bf2f((u16)(w.w & 0xFFFFu)); a[7] += bf2f((u16)(w.w >> 16));
}

// Bin edges into per-bucket staging. NO per-node atomics; single pass.
// 1024 threads/block (2 edges/thread): ~24 waves/CU avg for latency hiding.
// bucket(d) = d >> BSH. Entry: src | (d&255)<<16.
__global__ __launch_bounds__(1024) void k_binA2(
    const int* __restrict__ src, const int* __restrict__ dst,
    int* __restrict__ gcur, u32* __restrict__ staging,
    u32* __restrict__ ovf, int* __restrict__ ovfcur, int E) {
    __shared__ int hcnt[256];
    __shared__ int hbase[256];
    const int tid = threadIdx.x;
    const int e0 = blockIdx.x * CHUNK;
    const int e1 = min(e0 + CHUNK, E);
    if (tid < 256) hcnt[tid] = 0;
    __syncthreads();
    int dl[2], sl[2];
    const int eb = e0 + tid * 2;
    const bool vec = (eb + 1 < e1) &&
                     ((((size_t)(dst + eb)) | ((size_t)(src + eb))) & 7) == 0;
    if (vec) {
        int2 d2 = *(const int2*)(dst + eb);
        int2 s2 = *(const int2*)(src + eb);
        dl[0] = d2.x; dl[1] = d2.y;
        sl[0] = s2.x; sl[1] = s2.y;
    } else {
#pragma unroll
        for (int k = 0; k < 2; k++) {
            int e = eb + k;
            bool ok = e < e1;
            dl[k] = ok ? dst[e] : -1;
            sl[k] = ok ? src[e] : 0;
        }
    }
#pragma unroll
    for (int k = 0; k < 2; k++)
        if (dl[k] >= 0) atomicAdd(&hcnt[dl[k] >> BSH], 1);
    __syncthreads();
    if (tid < 256) {
        int c = hcnt[tid];
        hbase[tid] = (c > 0) ? atomicAdd(&gcur[tid], c) : 0;
        hcnt[tid] = 0;                   // reuse as local cursor
    }
    __syncthreads();
#pragma unroll
    for (int k = 0; k < 2; k++) {
        int d = dl[k];
        if (d < 0) continue;
        int b = d >> BSH;
        int r = atomicAdd(&hcnt[b], 1);
        int p = hbase[b] + r;
        if (p < CAP) {
            staging[(size_t)b * CAP + p] = (u32)sl[k] | ((u32)(d & 255) << 16);
        } else {
            int q = atomicAdd(ovfcur, 1);
            if (q < OVFCAP) ovf[q] = (u32)sl[k] | ((u32)d << 16);
        }
    }
}

// Per-bucket counting sort. One 1024-thread block per bucket.
// Staging is read ONCE into registers (<=2 uint4/thread + scalar tail), feeding
// both the hist and the fill. csr goes through an LDS segment buffer for
// coalesced global writes. Blocks [nbuck, nbuck+17): weight canonicalization.
// wc layout (u16): [0,8192) W1t[n*64+k] | [8192,16384) W2t[n*128+k]
//                  [16384,16512) b1 | [16512,16576) b2
__global__ __launch_bounds__(1024) void k_bucket(
    const u32* __restrict__ staging, const int* __restrict__ gcur,
    const u32* __restrict__ ovf, const int* __restrict__ ovfcur,
    int* __restrict__ row_start, float* __restrict__ dinv,
    u16* __restrict__ csr, int nbuck,
    const void* __restrict__ W1, const void* __restrict__ b1,
    const void* __restrict__ W2, const void* __restrict__ b2,
    u16* __restrict__ wc,
    const void* __restrict__ x, u16* __restrict__ gxt, int N, int E) {
    __shared__ float sflag;
    __shared__ int hcnt[256];
    __shared__ int hscan[256];
    __shared__ int hcur[256];
    __shared__ int sred[256];
    __shared__ int sbase;
    __shared__ float sdinv[256];
    __shared__ u16 seg_lds[SEGCAP];   // 12 KB: cursor-ordered csr segment
    const int bid = blockIdx.x;
    const int tid = threadIdx.x;
    bool isbf = block_isbf((const u16*)x, &sflag);

    if (bid < nbuck) {
        const int b = bid;
        const int used = min(gcur[b], CAP);
        const u32* st = staging + (size_t)b * CAP;
        const int no = min(ovfcur[0], OVFCAP);
        const int used4 = used >> 2;
        // bucket base = sum gcur[0..b)
        if (tid < 256) {
            sred[tid] = (tid < b) ? gcur[tid] : 0;
            hcnt[tid] = 0;
        }
        __syncthreads();
        for (int s = 128; s > 0; s >>= 1) {
            if (tid < s) sred[tid] += sred[tid + s];
            __syncthreads();
        }
        if (tid == 0) sbase = sred[0];
        // register-cache staging (single global read feeds hist AND fill)
        const int i0 = tid, i1 = 1024 + tid;
        const bool h0 = i0 < used4, h1 = i1 < used4;
        uint4 r0v = h0 ? ((const uint4*)st)[i0] : make_uint4(0, 0, 0, 0);
        uint4 r1v = h1 ? ((const uint4*)st)[i1] : make_uint4(0, 0, 0, 0);
        const int ti = (used4 << 2) + tid;
        const bool ht = ti < used;
        u32 tv = ht ? st[ti] : 0u;
        // pass1: per-node hist
        if (h0) {
            atomicAdd(&hcnt[r0v.x >> 16], 1);
            atomicAdd(&hcnt[r0v.y >> 16], 1);
            atomicAdd(&hcnt[r0v.z >> 16], 1);
            atomicAdd(&hcnt[r0v.w >> 16], 1);
        }
        if (h1) {
            atomicAdd(&hcnt[r1v.x >> 16], 1);
            atomicAdd(&hcnt[r1v.y >> 16], 1);
            atomicAdd(&hcnt[r1v.z >> 16], 1);
            atomicAdd(&hcnt[r1v.w >> 16], 1);
        }
        if (ht) atomicAdd(&hcnt[tv >> 16], 1);
        for (int i = tid; i < no; i += 1024) {
            u32 pk = ovf[i];
            int d = (int)(pk >> 16);
            if ((d >> BSH) == b) atomicAdd(&hcnt[d & 255], 1);
        }
        __syncthreads();
        // exclusive scan over 256 counts (guarded; barriers uniform)
        int v = 0;
        if (tid < 256) {
            v = hcnt[tid];
            hscan[tid] = v;
        }
        __syncthreads();
        for (int s = 1; s < 256; s <<= 1) {
            int t = (tid < 256 && tid >= s) ? hscan[tid - s] : 0;
            __syncthreads();
            if (tid < 256) hscan[tid] += t;
            __syncthreads();
        }
        if (tid < 256) {
            int excl = hscan[tid] - v;
            hcur[tid] = excl;
            float dv = rsqrtf((float)(v + 1));
            sdinv[tid] = dv;
            int node = (b << BSH) + tid;
            if (node < N) {
                row_start[node] = sbase + excl;
                dinv[node] = dv;
            }
        }
        if (b == 0 && tid == 0) row_start[N] = E;
        __syncthreads();
        const int base = sbase;
        // pass2: csr fill from registers via LDS cursors into LDS segment
        if (h0) {
            int r0 = atomicAdd(&hcur[r0v.x >> 16], 1);
            u16 w0 = (u16)(r0v.x & 0xFFFFu);
            if (r0 < SEGCAP) seg_lds[r0] = w0; else csr[base + r0] = w0;
            int r1 = atomicAdd(&hcur[r0v.y >> 16], 1);
            u16 w1 = (u16)(r0v.y & 0xFFFFu);
            if (r1 < SEGCAP) seg_lds[r1] = w1; else csr[base + r1] = w1;
            int r2 = atomicAdd(&hcur[r0v.z >> 16], 1);
            u16 w2 = (u16)(r0v.z & 0xFFFFu);
            if (r2 < SEGCAP) seg_lds[r2] = w2; else csr[base + r2] = w2;
            int r3 = atomicAdd(&hcur[r0v.w >> 16], 1);
            u16 w3 = (u16)(r0v.w & 0xFFFFu);
            if (r3 < SEGCAP) seg_lds[r3] = w3; else csr[base + r3] = w3;
        }
        if (h1) {
            int r0 = atomicAdd(&hcur[r1v.x >> 16], 1);
            u16 w0 = (u16)(r1v.x & 0xFFFFu);
            if (r0 < SEGCAP) seg_lds[r0] = w0; else csr[base + r0] = w0;
            int r1 = atomicAdd(&hcur[r1v.y >> 16], 1);
            u16 w1 = (u16)(r1v.y & 0xFFFFu);
            if (r1 < SEGCAP) seg_lds[r1] = w1; else csr[base + r1] = w1;
            int r2 = atomicAdd(&hcur[r1v.z >> 16], 1);
            u16 w2 = (u16)(r1v.z & 0xFFFFu);
            if (r2 < SEGCAP) seg_lds[r2] = w2; else csr[base + r2] = w2;
            int r3 = atomicAdd(&hcur[r1v.w >> 16], 1);
            u16 w3 = (u16)(r1v.w & 0xFFFFu);
            if (r3 < SEGCAP) seg_lds[r3] = w3; else csr[base + r3] = w3;
        }
        if (ht) {
            int r = atomicAdd(&hcur[tv >> 16], 1);
            u16 w = (u16)(tv & 0xFFFFu);
            if (r < SEGCAP) seg_lds[r] = w; else csr[base + r] = w;
        }
        for (int i = tid; i < no; i += 1024) {
            u32 pk = ovf[i];
            int d = (int)(pk >> 16);
            if ((d >> BSH) == b) {
                int r = atomicAdd(&hcur[d & 255], 1);
                u16 w = (u16)(pk & 0xFFFFu);
                if (r < SEGCAP) seg_lds[r] = w; else csr[base + r] = w;
            }
        }
        __syncthreads();
        // coalesced dump of the segment
        {
            int seg = min(hscan[255], SEGCAP);
            for (int i = tid; i < seg; i += 1024) csr[base + i] = seg_lds[i];
        }
        // scale_x for our 256 rows: gxt[row] = bf16(x[row] * dinv[row])
        const int row0 = b << BSH;
        for (int i = tid; i < 256 * 16; i += 1024) {
            int rl = i >> 4;
            int node2 = row0 + rl;
            if (node2 >= N) continue;
            int q = i & 15;
            size_t idx = (size_t)node2 * 16 + q;
            float di = sdinv[rl];
            float4 vv;
            if (isbf) {
                ushort4 u = ((const ushort4*)x)[idx];
                vv.x = bf2f(u.x); vv.y = bf2f(u.y); vv.z = bf2f(u.z); vv.w = bf2f(u.w);
            } else {
                vv = ((const float4*)x)[idx];
            }
            ushort4 o;
            o.x = f2bf(vv.x * di); o.y = f2bf(vv.y * di);
            o.z = f2bf(vv.z * di); o.w = f2bf(vv.w * di);
            ((ushort4*)gxt)[idx] = o;
        }
    } else {
        // weight canonicalize (17 blocks, one stride covers 16576)
        int cb = bid - nbuck;
        for (int i = cb * 1024 + tid; i < 16576; i += 17 * 1024) {
            const void* s; int off;
            if (i < 8192)       { int nn = i >> 6, k = i & 63;  s = W1; off = k * 128 + nn; }
            else if (i < 16384) { int j = i - 8192; int nn = j >> 7, k = j & 127; s = W2; off = k * 64 + nn; }
            else if (i < 16512) { s = b1; off = i - 16384; }
            else                { s = b2; off = i - 16512; }
            wc[i] = isbf ? ((const u16*)s)[off] : f2bf(((const float*)s)[off]);
        }
    }
}

// gather: acc[d] = feat[d] + sum_{j in in(d)} feat[csr[j]], then *dinv[d]
// (+b2 and dtype-matched output when FINAL).
// 8 lanes per node, uint4 loads; csr indices software-pipelined. High occupancy
// (tiny LDS) is essential: this kernel is latency-bound random access.
// (Round-4 column-split experiment REGRESSED +19us: cost is visit-count-
//  latency, not bytes/L2 capacity. Keep single-pass full-row form.)
template<bool FINAL>
__global__ __launch_bounds__(256) void k_gather(
    const uint4* __restrict__ feat, const int* __restrict__ row_start,
    const u16* __restrict__ csr, const float* __restrict__ dinv,
    const u16* __restrict__ b2c, const void* __restrict__ xdet,
    void* __restrict__ outp, int n) {
    __shared__ float sflag;
    bool isbf = true;
    if (FINAL) isbf = block_isbf((const u16*)xdet, &sflag);
    int t = blockIdx.x * 256 + threadIdx.x;
    int d = t >> 3;
    int lane = t & 7;            // 8 lanes/node, lane covers feats [8*lane, 8*lane+8)
    if (d >= n) return;
    const uint4* fl = feat + lane;   // row = 8 uint4
    float a[8];
    {
        uint4 w = fl[(size_t)d * 8];     // self-loop
        a[0] = bf2f((u16)(w.x & 0xFFFFu)); a[1] = bf2f((u16)(w.x >> 16));
        a[2] = bf2f((u16)(w.y & 0xFFFFu)); a[3] = bf2f((u16)(w.y >> 16));
        a[4] = bf2f((u16)(w.z & 0xFFFFu)); a[5] = bf2f((u16)(w.z >> 16));
        a[6] = bf2f((u16)(w.w & 0xFFFFu)); a[7] = bf2f((u16)(w.w >> 16));
    }
    int s0 = row_start[d], s1 = row_start[d + 1];
    int j = s0;
    int cur = (j + lane < s1) ? (int)csr[j + lane] : 0;
    while (j + 8 <= s1) {
        int nxt = (j + 8 + lane < s1) ? (int)csr[j + 8 + lane] : 0;
        uint4 wv[8];
#pragma unroll
        for (int u = 0; u < 8; u++) {
            int sv = __shfl(cur, u, 8);
            wv[u] = fl[(size_t)sv * 8];
        }
#pragma unroll
        for (int u = 0; u < 8; u++) acc8(wv[u], a);
        cur = nxt;
        j += 8;
    }
    int rem = s1 - j;
    if (rem > 0) {
        for (int u = 0; u < rem; u++) {
            int sv = __shfl(cur, u, 8);
            uint4 wv = fl[(size_t)sv * 8];
            acc8(wv, a);
        }
    }
    float di = dinv[d];
    if (FINAL) {
#pragma unroll
        for (int u = 0; u < 8; u++)
            a[u] = a[u] * di + bf2f(b2c[8 * lane + u]);
        if (isbf) {
            uint4 o;
            o.x = (u32)f2bf(a[0]) | ((u32)f2bf(a[1]) << 16);
            o.y = (u32)f2bf(a[2]) | ((u32)f2bf(a[3]) << 16);
            o.z = (u32)f2bf(a[4]) | ((u32)f2bf(a[5]) << 16);
            o.w = (u32)f2bf(a[6]) | ((u32)f2bf(a[7]) << 16);
            ((uint4*)outp)[(size_t)d * 8 + lane] = o;
        } else {
            float4* op = (float4*)outp;
            op[(size_t)d * 16 + 2 * lane]     = make_float4(a[0], a[1], a[2], a[3]);
            op[(size_t)d * 16 + 2 * lane + 1] = make_float4(a[4], a[5], a[6], a[7]);
        }
    } else {
        // single rounding: fp32 acc * dinv -> bf16 (k_mlp consumes directly)
        uint4 o;
        o.x = (u32)f2bf(a[0] * di) | ((u32)f2bf(a[1] * di) << 16);
        o.y = (u32)f2bf(a[2] * di) | ((u32)f2bf(a[3] * di) << 16);
        o.z = (u32)f2bf(a[4] * di) | ((u32)f2bf(a[5] * di) << 16);
        o.w = (u32)f2bf(a[6] * di) | ((u32)f2bf(a[7] * di) << 16);
        ((uint4*)outp)[(size_t)d * 8 + lane] = o;
    }
}

// MFMA fused 2-layer MLP on a 64-row tile, LDS-MINIMAL version:
// A- and B-fragments are loaded DIRECTLY from global (wc and accin are L2-hot;
// per-wave slices are coalesced 16-row x 64 B segments) — no As/W1t/W2t LDS
// staging. Only Hs (GEMM1->GEMM2 transpose, 17.4 KB) + dvs live in LDS:
// 44.8 KB -> 17.7 KB, occupancy 3 -> ~4 blocks/CU (VGPR-capped), ONE barrier.
// Values and rounding points identical to the staged version.
__global__ __launch_bounds__(256) void k_mlp(
    const u16* __restrict__ accin, const u16* __restrict__ wc,
    const float* __restrict__ dinv, u16* outb, int n) {
    __shared__ __align__(16) u16 Hs[64 * 136];            // 17.0 KB
    __shared__ float dvs[64];

    const int tid = threadIdx.x;
    const int row0 = blockIdx.x * 64;

    if (tid < 64) {
        int r = row0 + tid;
        dvs[tid] = (r < n) ? dinv[r] : 0.f;
    }

    const int wave = tid >> 6;     // 0..3
    const int lane = tid & 63;
    const int q = lane >> 4;       // quad
    const int ln = lane & 15;

    // ---- GEMM1: [64x64] @ [64x128] ----
    // A-frags straight from accin (acc1 already dinv-prescaled, bf16)
    bf16x8 a[4][2];
#pragma unroll
    for (int mt = 0; mt < 4; mt++) {
        int row = row0 + mt * 16 + ln;
        if (row < n) {
#pragma unroll
            for (int ks = 0; ks < 2; ks++)
                a[mt][ks] = *(const bf16x8*)&accin[(size_t)row * 64 + ks * 32 + q * 8];
        } else {
#pragma unroll
            for (int ks = 0; ks < 2; ks++)
                a[mt][ks] = (bf16x8){0, 0, 0, 0, 0, 0, 0, 0};
        }
    }

    f32x4 c1[2][4];   // [ntl][mt]
#pragma unroll
    for (int ntl = 0; ntl < 2; ntl++)
#pragma unroll
        for (int mt = 0; mt < 4; mt++) c1[ntl][mt] = (f32x4){0.f, 0.f, 0.f, 0.f};

    __builtin_amdgcn_s_setprio(1);
#pragma unroll
    for (int ntl = 0; ntl < 2; ntl++) {
        int nt = wave * 2 + ntl;
        // B-frags straight from wc (W1t: row stride 64 u16, L2-hot)
        bf16x8 b0  = *(const bf16x8*)&wc[(nt * 16 + ln) * 64 + 0 + q * 8];
        bf16x8 b1f = *(const bf16x8*)&wc[(nt * 16 + ln) * 64 + 32 + q * 8];
#pragma unroll
        for (int mt = 0; mt < 4; mt++) {
            c1[ntl][mt] = __builtin_amdgcn_mfma_f32_16x16x32_bf16(a[mt][0], b0, c1[ntl][mt], 0, 0, 0);
            c1[ntl][mt] = __builtin_amdgcn_mfma_f32_16x16x32_bf16(a[mt][1], b1f, c1[ntl][mt], 0, 0, 0);
        }
    }
    __builtin_amdgcn_s_setprio(0);
#pragma unroll
    for (int ntl = 0; ntl < 2; ntl++) {
        int col = (wave * 2 + ntl) * 16 + ln;
        float bb = bf2f(wc[16384 + col]);    // b1, L2-hot scalar
#pragma unroll
        for (int mt = 0; mt < 4; mt++)
#pragma unroll
            for (int r = 0; r < 4; r++) {
                int hrow = mt * 16 + q * 4 + r;
                Hs[hrow * 136 + col] = f2bf(fmaxf(c1[ntl][mt][r] + bb, 0.f));
            }
    }
    __syncthreads();               // Hs (and dvs) ready

    // ---- GEMM2: [64x128] @ [128x64] ----
    const u16* wc2 = wc + 8192;    // W2t: row stride 128 u16
    f32x4 c2[4];
#pragma unroll
    for (int mt = 0; mt < 4; mt++) c2[mt] = (f32x4){0.f, 0.f, 0.f, 0.f};
    __builtin_amdgcn_s_setprio(1);
#pragma unroll
    for (int ks = 0; ks < 4; ks++) {
        bf16x8 bb = *(const bf16x8*)&wc2[(wave * 16 + ln) * 128 + ks * 32 + q * 8];
#pragma unroll
        for (int mt = 0; mt < 4; mt++) {
            bf16x8 aa = *(const bf16x8*)&Hs[(mt * 16 + ln) * 136 + ks * 32 + q * 8];
            c2[mt] = __builtin_amdgcn_mfma_f32_16x16x32_bf16(aa, bb, c2[mt], 0, 0, 0);
        }
    }
    __builtin_amdgcn_s_setprio(0);
#pragma unroll
    for (int mt = 0; mt < 4; mt++)
#pragma unroll
        for (int r = 0; r < 4; r++) {
            int rloc = mt * 16 + q * 4 + r;
            int row = row0 + rloc;
            if (row < n) {
                int col = wave * 16 + ln;
                outb[(size_t)row * 64 + col] = f2bf(c2[mt][r] * dvs[rloc]);
            }
        }
}

extern "C" void kernel_launch(void* const* d_in, const int* in_sizes, int n_in,
                              void* d_out, int out_size, void* d_ws, size_t ws_size,
                              hipStream_t stream) {
    const void* x  = d_in[0];
    const int* ei  = (const int*)d_in[1];
    const void* W1 = d_in[2];
    const void* b1 = d_in[3];
    const void* W2 = d_in[4];
    const void* b2 = d_in[5];

    const int N = in_sizes[0] / 64;   // 50000 (< 65536 required: u16 csr + packing)
    const int E = in_sizes[1] / 2;    // 800000
    const int* src = ei;
    const int* dst = ei + E;

    // workspace (~8.5 MB of d_ws):
    //   dinv[NP] | gcur[256] | ovfcur[+pad 64] | row_start[N+64] | ovf[8192] u32
    //   | csr[E] u16 | wc[16576] u16 | bufB (N*64 u16)
    // staging (nbuck*CAP u32 ~4 MB) aliases bufB (dead until k_mlp writes it).
    // xt lives in d_out (scratch until k_gather<true> rewrites it).
    float* ws = (float*)d_ws;
    const int NP = ((N + 64) + 63) & ~63;
    float* dinv    = ws;
    int* gcur      = (int*)(ws + NP);
    int* ovfcur    = gcur + 256;
    int* row_start = gcur + 320;
    u32* ovf       = (u32*)(row_start + ((N + 64) & ~63));
    u16* csr       = (u16*)(ovf + OVFCAP);
    u16* wc        = (u16*)(((size_t)(csr + E) + 255) & ~(size_t)255);
    u16* bufB      = (u16*)(((size_t)(wc + 16576) + 255) & ~(size_t)255);
    u32* staging   = (u32*)bufB;
    u16* gxt       = (u16*)d_out;

    const int gth = (N * 8 + 255) / 256;       // gather grid (8 lanes/node)
    const int nbuck = (N + 255) >> BSH;        // 196 (<=256 required)
    const int binB = (E + CHUNK - 1) / CHUNK;  // 391
    dim3 blk(256);
    dim3 blk1k(1024);

    // zero gcur + ovfcur (graph-capture legal)
    hipMemsetAsync(gcur, 0, 320 * sizeof(int), stream);
    // bin edges into per-bucket staging (no per-node atomics, single-pass)
    k_binA2<<<dim3(binB), blk1k, 0, stream>>>(src, dst, gcur, staging, ovf, ovfcur, E);
    // per-bucket counting sort (row_start/dinv/csr) + scale_x + weight canon
    k_bucket<<<dim3(nbuck + 17), blk1k, 0, stream>>>(staging, gcur, ovf, ovfcur,
                                                     row_start, dinv, csr, nbuck,
                                                     W1, b1, W2, b2, wc, x, gxt, N, E);
    // acc1 = gather(xt)*dinv -> bufB (staging now dead)
    k_gather<false><<<dim3(gth), blk, 0, stream>>>((const uint4*)gxt, row_start, csr,
                                                   dinv, wc + 16512, x, bufB, N);
    // ht2 = (relu(acc1 @ W1 + b1) @ W2)*dinv -> bufB (in-place, row-local)
    k_mlp<<<dim3((N + 63) / 64), blk, 0, stream>>>((const u16*)bufB, wc, dinv, bufB, N);
    // out = bf16/f32( (ht2[d]+gather(ht2))*dinv + b2 ) -> d_out
    k_gather<true><<<dim3(gth), blk, 0, stream>>>((const uint4*)bufB, row_start, csr,
                                                  dinv, wc + 16512, x, d_out, N);
}